// Round 2
// baseline (3607.619 us; speedup 1.0000x reference)
//
#include <hip/hip_runtime.h>
#include <hip/hip_bf16.h>
#include <cstdint>

#define NNODES 50000
#define NEDGES 800000
#define DFEAT  128
#define NMSG   21

typedef __attribute__((ext_vector_type(8))) short  s16x8;
typedef __attribute__((ext_vector_type(4))) float  f32x4;
typedef __attribute__((ext_vector_type(8))) float  f32x8;

__device__ __forceinline__ unsigned short f2bf(float f) {
    unsigned int u = __float_as_uint(f);
    unsigned int r = (u + 0x7fffu + ((u >> 16) & 1u)) >> 16;   // round-to-nearest-even
    return (unsigned short)r;
}
__device__ __forceinline__ float bf2f(unsigned short b) {
    return __uint_as_float(((unsigned int)b) << 16);
}

// ---------------- CSR build ----------------
__global__ void hist_kernel(const int* __restrict__ dst, int* counts) {
    int e = blockIdx.x * blockDim.x + threadIdx.x;
    if (e < NEDGES) atomicAdd(&counts[dst[e]], 1);
}

__global__ void scan_kernel(const int* __restrict__ counts, int* __restrict__ row_start,
                            int* __restrict__ cursor) {
    __shared__ int sd[1024];
    int tid = threadIdx.x;
    int running = 0;
    for (int base = 0; base < NNODES; base += 1024) {
        int i = base + tid;
        int c = (i < NNODES) ? counts[i] : 0;
        sd[tid] = c;
        __syncthreads();
        for (int off = 1; off < 1024; off <<= 1) {
            int v = (tid >= off) ? sd[tid - off] : 0;
            __syncthreads();
            sd[tid] += v;
            __syncthreads();
        }
        int incl = sd[tid];
        if (i < NNODES) {
            int ex = running + incl - c;
            row_start[i] = ex;
            cursor[i]    = ex;
        }
        running += sd[1023];
        __syncthreads();
    }
    if (tid == 0) row_start[NNODES] = running;
}

__global__ void scatter_kernel(const int* __restrict__ src, const int* __restrict__ dst,
                               int* cursor, int* __restrict__ colv) {
    int e = blockIdx.x * blockDim.x + threadIdx.x;
    if (e < NEDGES) {
        int d   = dst[e];
        int pos = atomicAdd(&cursor[d], 1);
        colv[pos] = src[e];
    }
}

// ---------------- weight prep: fp32 -> frag-linear bf16 hi/lo ----------------
// frag layout per matrix: [kk][nt][lane][i] flat; value = W[nt*16+(lane&15)][kk*32+(lane>>4)*8+i]
__global__ void prep_wmsg(const float* __restrict__ W, unsigned short* __restrict__ hi,
                          unsigned short* __restrict__ lo) {
    int idx = blockIdx.x * blockDim.x + threadIdx.x;
    const int per = 4 * 8 * 512;               // KK=4, NT=8
    if (idx >= NMSG * per) return;
    int layer = idx / per;
    int r     = idx % per;
    int kk    = r / 4096;
    int nt    = (r / 512) & 7;
    int lane  = (r / 8) & 63;
    int i     = r & 7;
    int c = nt * 16 + (lane & 15);
    int k = kk * 32 + (lane >> 4) * 8 + i;
    float w = W[(size_t)layer * 16384 + c * 128 + k];
    unsigned short h = f2bf(w);
    hi[idx] = h;
    lo[idx] = f2bf(w - bf2f(h));
}

__global__ void prep_wupd(const float* __restrict__ W, unsigned short* __restrict__ hi,
                          unsigned short* __restrict__ lo) {
    int idx = blockIdx.x * blockDim.x + threadIdx.x;
    const int per = 8 * 8 * 512;               // KK=8, NT=8
    if (idx >= NMSG * per) return;
    int layer = idx / per;
    int r     = idx % per;
    int kk    = r / 4096;
    int nt    = (r / 512) & 7;
    int lane  = (r / 8) & 63;
    int i     = r & 7;
    int c = nt * 16 + (lane & 15);
    int k = kk * 32 + (lane >> 4) * 8 + i;
    float w = W[(size_t)layer * 32768 + c * 256 + k];
    unsigned short h = f2bf(w);
    hi[idx] = h;
    lo[idx] = f2bf(w - bf2f(h));
}

__global__ void prep_mlp(const float* __restrict__ W1, const float* __restrict__ W2,
                         const float* __restrict__ W3,
                         unsigned short* w1h, unsigned short* w1l,
                         unsigned short* w2h, unsigned short* w2l,
                         unsigned short* w3h, unsigned short* w3l) {
    int idx = blockIdx.x * blockDim.x + threadIdx.x;
    if (idx >= 73728) return;
    const float* W; unsigned short *ph, *pl; int NT, Kld, nc, local;
    if (idx < 32768)      { local = idx;          W = W1; ph = w1h; pl = w1l; NT = 16; Kld = 128; nc = 256; }
    else if (idx < 65536) { local = idx - 32768;  W = W2; ph = w2h; pl = w2l; NT = 8;  Kld = 256; nc = 128; }
    else                  { local = idx - 65536;  W = W3; ph = w3h; pl = w3l; NT = 4;  Kld = 128; nc = 63;  }
    int i    = local & 7;
    int lane = (local >> 3) & 63;
    int nt   = (local >> 9) % NT;
    int kk   = local / (512 * NT);
    int c = nt * 16 + (lane & 15);
    int k = kk * 32 + (lane >> 4) * 8 + i;
    float w = (c < nc) ? W[c * Kld + k] : 0.f;
    unsigned short h = f2bf(w);
    ph[local] = h;
    pl[local] = f2bf(w - bf2f(h));
}

// ---------------- GEMM: C[M,Nout] = act(A[M,K] @ W^T + bias), split bf16 MFMA ----------------
// A = [A1 (k1 cols) | A2 (k2 cols)] row-major fp32. B frags prepped per above.
// ACT: 0 none, 1 relu, 2 tanh
template <int NT, int MT, int ACT, bool HAS_BIAS>
__global__ __launch_bounds__(256) void gemm_mfma(
    const float* __restrict__ A1, const float* __restrict__ A2, int k1, int k2,
    const unsigned short* __restrict__ Bhi, const unsigned short* __restrict__ Blo,
    const float* __restrict__ bias,
    float* __restrict__ C, int M, int ldc, int ncols)
{
    int lane = threadIdx.x & 63;
    int w    = threadIdx.x >> 6;
    int waveRow0 = blockIdx.x * (MT * 64) + w * (MT * 16);
    int KK = (k1 + k2) >> 5;

    f32x4 acc[MT][NT];
#pragma unroll
    for (int mi = 0; mi < MT; ++mi)
#pragma unroll
        for (int nt = 0; nt < NT; ++nt)
#pragma unroll
            for (int j = 0; j < 4; ++j) acc[mi][nt][j] = 0.f;

    int lm = lane & 15;
    int lk = (lane >> 4) * 8;

    for (int kk = 0; kk < KK; ++kk) {
        int kbase = kk * 32;
        const float* ap; int kb, ld;
        if (kbase < k1) { ap = A1; kb = kbase;      ld = k1; }
        else            { ap = A2; kb = kbase - k1; ld = k2; }
        int kcol = kb + lk;

        s16x8 ahi[MT], alo[MT];
#pragma unroll
        for (int mi = 0; mi < MT; ++mi) {
            int row = waveRow0 + mi * 16 + lm;
            f32x8 v;
            if (row < M) {
                v = *reinterpret_cast<const f32x8*>(ap + (size_t)row * ld + kcol);
            } else {
#pragma unroll
                for (int i = 0; i < 8; ++i) v[i] = 0.f;
            }
#pragma unroll
            for (int i = 0; i < 8; ++i) {
                unsigned short h = f2bf(v[i]);
                ahi[mi][i] = (short)h;
                alo[mi][i] = (short)f2bf(v[i] - bf2f(h));
            }
        }

        const unsigned short* bp  = Bhi + ((size_t)kk * NT) * 512 + lane * 8;
        const unsigned short* bpl = Blo + ((size_t)kk * NT) * 512 + lane * 8;
#pragma unroll
        for (int nt = 0; nt < NT; ++nt) {
            s16x8 bh = *reinterpret_cast<const s16x8*>(bp  + nt * 512);
            s16x8 bl = *reinterpret_cast<const s16x8*>(bpl + nt * 512);
#pragma unroll
            for (int mi = 0; mi < MT; ++mi) {
                acc[mi][nt] = __builtin_amdgcn_mfma_f32_16x16x32_bf16(ahi[mi], bh, acc[mi][nt], 0, 0, 0);
                acc[mi][nt] = __builtin_amdgcn_mfma_f32_16x16x32_bf16(ahi[mi], bl, acc[mi][nt], 0, 0, 0);
                acc[mi][nt] = __builtin_amdgcn_mfma_f32_16x16x32_bf16(alo[mi], bh, acc[mi][nt], 0, 0, 0);
            }
        }
    }

    // epilogue: C/D layout: col = lane&15, row = (lane>>4)*4 + j   [measured m89]
    int cr = (lane >> 4) << 2;
#pragma unroll
    for (int mi = 0; mi < MT; ++mi) {
        int r0 = waveRow0 + mi * 16 + cr;
#pragma unroll
        for (int nt = 0; nt < NT; ++nt) {
            int col = nt * 16 + lm;
            if (col >= ncols) continue;
            float b = HAS_BIAS ? bias[col] : 0.f;
#pragma unroll
            for (int j = 0; j < 4; ++j) {
                int row = r0 + j;
                if (row < M) {
                    float v = acc[mi][nt][j] + b;
                    if (ACT == 1) v = v > 0.f ? v : 0.f;
                    else if (ACT == 2) v = tanhf(v);
                    C[(size_t)row * ldc + col] = v;
                }
            }
        }
    }
}

// ---------------- aggregation: aggr[n] = m[n] + sum_{e: dst=n} m[src[e]] ----------------
__global__ __launch_bounds__(256) void aggregate_kernel(
    const float* __restrict__ m, const int* __restrict__ row_start,
    const int* __restrict__ cols, float* __restrict__ aggr)
{
    int wid  = (blockIdx.x * blockDim.x + threadIdx.x) >> 6;
    int lane = threadIdx.x & 63;
    if (wid >= NNODES) return;
    int s0 = row_start[wid], s1 = row_start[wid + 1];
    const float* mr = m + (size_t)wid * DFEAT;
    float a0 = mr[lane];
    float a1 = mr[lane + 64];
    for (int e = s0; e < s1; ++e) {
        int s = cols[e];
        const float* ms = m + (size_t)s * DFEAT;
        a0 += ms[lane];
        a1 += ms[lane + 64];
    }
    float* ar = aggr + (size_t)wid * DFEAT;
    ar[lane]      = a0;
    ar[lane + 64] = a1;
}

// ---------------- host ----------------
extern "C" void kernel_launch(void* const* d_in, const int* in_sizes, int n_in,
                              void* d_out, int out_size, void* d_ws, size_t ws_size,
                              hipStream_t stream)
{
    const float* x     = (const float*)d_in[0];
    const int*   ei    = (const int*)d_in[1];      // harness delivers int inputs as int32
    const float* W_msg = (const float*)d_in[3];
    const float* b_msg = (const float*)d_in[4];
    const float* W_upd = (const float*)d_in[5];
    const float* W1    = (const float*)d_in[6];
    const float* b1    = (const float*)d_in[7];
    const float* W2    = (const float*)d_in[8];
    const float* b2    = (const float*)d_in[9];
    const float* W3    = (const float*)d_in[10];
    const float* b3    = (const float*)d_in[11];
    const int*   srcp  = ei;
    const int*   dstp  = ei + NEDGES;

    char* ws = (char*)d_ws;
    size_t off = 0;
    auto carve = [&](size_t bytes) -> void* {
        void* p = ws + off;
        off += (bytes + 255) & ~(size_t)255;
        return p;
    };
    const size_t NODE_BYTES = (size_t)NNODES * DFEAT * 4;   // 25,600,000 (multiple of 256)
    float* buf0 = (float*)carve(NODE_BYTES);
    float* buf1 = (float*)carve(NODE_BYTES);   // buf1,buf2 contiguous -> h1 (N x 256) overlay
    float* buf2 = (float*)carve(NODE_BYTES);   // aggr

    int* counts    = (int*)carve((size_t)NNODES * 4);
    int* cursor    = (int*)carve((size_t)NNODES * 4);
    int* row_start = (int*)carve(((size_t)NNODES + 1) * 4);
    int* colv      = (int*)carve((size_t)NEDGES * 4);

    unsigned short* wmsg_hi = (unsigned short*)carve((size_t)NMSG * 16384 * 2);
    unsigned short* wmsg_lo = (unsigned short*)carve((size_t)NMSG * 16384 * 2);
    unsigned short* wupd_hi = (unsigned short*)carve((size_t)NMSG * 32768 * 2);
    unsigned short* wupd_lo = (unsigned short*)carve((size_t)NMSG * 32768 * 2);
    unsigned short* w1_hi   = (unsigned short*)carve(32768 * 2);
    unsigned short* w1_lo   = (unsigned short*)carve(32768 * 2);
    unsigned short* w2_hi   = (unsigned short*)carve(32768 * 2);
    unsigned short* w2_lo   = (unsigned short*)carve(32768 * 2);
    unsigned short* w3_hi   = (unsigned short*)carve(8192 * 2);
    unsigned short* w3_lo   = (unsigned short*)carve(8192 * 2);

    // CSR build (per call; bucket order nondeterministic but only affects fp sum order)
    hipMemsetAsync(counts, 0, (size_t)NNODES * 4, stream);
    hist_kernel<<<(NEDGES + 255) / 256, 256, 0, stream>>>(dstp, counts);
    scan_kernel<<<1, 1024, 0, stream>>>(counts, row_start, cursor);
    scatter_kernel<<<(NEDGES + 255) / 256, 256, 0, stream>>>(srcp, dstp, cursor, colv);

    // weight prep
    prep_wmsg<<<(NMSG * 16384) / 256, 256, 0, stream>>>(W_msg, wmsg_hi, wmsg_lo);
    prep_wupd<<<(NMSG * 32768) / 256, 256, 0, stream>>>(W_upd, wupd_hi, wupd_lo);
    prep_mlp<<<73728 / 256, 256, 0, stream>>>(W1, W2, W3, w1_hi, w1_lo, w2_hi, w2_lo, w3_hi, w3_lo);

    // 21 message-passing layers; 3-buffer rotation:
    //   gemm1: hcur -> mb (tanh);  aggregate: mb -> buf2;  gemm2: (buf2|hcur) -> mb (relu)
    const float* hcur = x;     // x is (N,1,128) contiguous == (N,128)
    for (int l = 0; l < NMSG; ++l) {
        float* mb = (hcur == buf0) ? buf1 : buf0;
        gemm_mfma<8, 4, 2, true><<<196, 256, 0, stream>>>(
            hcur, nullptr, 128, 0,
            wmsg_hi + (size_t)l * 16384, wmsg_lo + (size_t)l * 16384,
            b_msg + (size_t)l * 128,
            mb, NNODES, 128, 128);
        aggregate_kernel<<<(NNODES * 64) / 256, 256, 0, stream>>>(mb, row_start, colv, buf2);
        gemm_mfma<8, 4, 1, false><<<196, 256, 0, stream>>>(
            buf2, hcur, 128, 128,
            wupd_hi + (size_t)l * 32768, wupd_lo + (size_t)l * 32768,
            nullptr,
            mb, NNODES, 128, 128);
        hcur = mb;
    }
    // after 21 layers hcur == buf0; buf1+buf2 free & contiguous

    float* h1 = buf1;          // N x 256 spans buf1+buf2
    float* h2 = buf0;          // reused after W1 gemm consumes it? -> no: W1 reads buf0, so
                               // write h2 only after W1 done (separate dispatch, same stream: ordered)
    gemm_mfma<16, 2, 1, true><<<(NNODES + 127) / 128, 256, 0, stream>>>(
        hcur, nullptr, 128, 0, w1_hi, w1_lo, b1, h1, NNODES, 256, 256);
    gemm_mfma<8, 4, 1, true><<<196, 256, 0, stream>>>(
        h1, nullptr, 256, 0, w2_hi, w2_lo, b2, h2, NNODES, 128, 128);
    gemm_mfma<4, 4, 0, true><<<196, 256, 0, stream>>>(
        h2, nullptr, 128, 0, w3_hi, w3_lo, b3, (float*)d_out, NNODES, 63, 63);
}

// Round 3
// 3131.577 us; speedup vs baseline: 1.1520x; 1.1520x over previous
//
#include <hip/hip_runtime.h>
#include <cstdint>

#define NN 50000
#define NE 800000

typedef __attribute__((ext_vector_type(8))) short  s16x8;
typedef __attribute__((ext_vector_type(4))) float  f32x4;
typedef __attribute__((ext_vector_type(4))) unsigned short u16x4;

__device__ __forceinline__ unsigned short f2bf(float f){
    unsigned u = __float_as_uint(f);
    return (unsigned short)((u + 0x7fffu + ((u >> 16) & 1u)) >> 16);   // RNE
}
__device__ __forceinline__ float bf2f(unsigned short b){ return __uint_as_float(((unsigned)b) << 16); }

// ================= CSR build =================
__global__ void hist_kernel(const int* __restrict__ dst, int* counts){
    int e = blockIdx.x * blockDim.x + threadIdx.x;
    if (e < NE) atomicAdd(&counts[dst[e]], 1);
}

__global__ void blocksum_kernel(const int* __restrict__ counts, int* __restrict__ bsum){
    __shared__ int sd[256];
    int i = blockIdx.x * 256 + threadIdx.x;
    int c = (i < NN) ? counts[i] : 0;
    sd[threadIdx.x] = c; __syncthreads();
    for (int o = 128; o > 0; o >>= 1){
        if (threadIdx.x < o) sd[threadIdx.x] += sd[threadIdx.x + o];
        __syncthreads();
    }
    if (threadIdx.x == 0) bsum[blockIdx.x] = sd[0];
}

__global__ void scanb_kernel(const int* __restrict__ bsum, int* __restrict__ boff,
                             int* __restrict__ row_start, int nb){
    __shared__ int sd[256];
    int t = threadIdx.x;
    int v = (t < nb) ? bsum[t] : 0;
    sd[t] = v; __syncthreads();
    for (int o = 1; o < 256; o <<= 1){
        int u = (t >= o) ? sd[t - o] : 0;
        __syncthreads();
        sd[t] += u;
        __syncthreads();
    }
    if (t < nb) boff[t] = sd[t] - v;   // exclusive
    if (t == 0) row_start[NN] = NE;
}

__global__ void localscan_kernel(const int* __restrict__ counts, const int* __restrict__ boff,
                                 int* __restrict__ row_start, int* __restrict__ cursor){
    __shared__ int sd[256];
    int t = threadIdx.x, i = blockIdx.x * 256 + t;
    int c = (i < NN) ? counts[i] : 0;
    sd[t] = c; __syncthreads();
    for (int o = 1; o < 256; o <<= 1){
        int u = (t >= o) ? sd[t - o] : 0;
        __syncthreads();
        sd[t] += u;
        __syncthreads();
    }
    if (i < NN){
        int ex = boff[blockIdx.x] + sd[t] - c;
        row_start[i] = ex; cursor[i] = ex;
    }
}

__global__ void scatter_kernel(const int* __restrict__ src, const int* __restrict__ dst,
                               int* cursor, int* __restrict__ colv){
    int e = blockIdx.x * blockDim.x + threadIdx.x;
    if (e < NE){
        int pos = atomicAdd(&cursor[dst[e]], 1);
        colv[pos] = src[e];
    }
}

// ================= x -> hi/lo =================
__global__ void convert_x_kernel(const float* __restrict__ x,
                                 unsigned short* __restrict__ xh, unsigned short* __restrict__ xl){
    int i = blockIdx.x * blockDim.x + threadIdx.x;
    if (i >= NN * 128 / 4) return;
    f32x4 v = *reinterpret_cast<const f32x4*>(x + (size_t)i * 4);
    u16x4 h, l;
#pragma unroll
    for (int j = 0; j < 4; ++j){
        unsigned short hh = f2bf(v[j]);
        h[j] = hh;
        l[j] = f2bf(v[j] - bf2f(hh));
    }
    *reinterpret_cast<u16x4*>(xh + (size_t)i * 4) = h;
    *reinterpret_cast<u16x4*>(xl + (size_t)i * 4) = l;
}

// ================= weight prep (fp32 -> frag-linear bf16 hi/lo) =================
// frag value = W[nt*16+(lane&15)][kk*32+(lane>>4)*8+i], flat [kk][nt][lane][i]
__global__ void prep_wmsg(const float* __restrict__ W, unsigned short* __restrict__ hi,
                          unsigned short* __restrict__ lo){
    int idx = blockIdx.x * blockDim.x + threadIdx.x;
    const int per = 4 * 8 * 512;
    if (idx >= 21 * per) return;
    int layer = idx / per, r = idx % per;
    int kk = r / 4096, nt = (r / 512) & 7, lane = (r / 8) & 63, i = r & 7;
    int c = nt * 16 + (lane & 15);
    int k = kk * 32 + (lane >> 4) * 8 + i;
    float w = W[(size_t)layer * 16384 + c * 128 + k];
    unsigned short h = f2bf(w);
    hi[idx] = h; lo[idx] = f2bf(w - bf2f(h));
}

__global__ void prep_wupd(const float* __restrict__ W, unsigned short* __restrict__ hi,
                          unsigned short* __restrict__ lo){
    int idx = blockIdx.x * blockDim.x + threadIdx.x;
    const int per = 8 * 8 * 512;
    if (idx >= 21 * per) return;
    int layer = idx / per, r = idx % per;
    int kk = r / 4096, nt = (r / 512) & 7, lane = (r / 8) & 63, i = r & 7;
    int c = nt * 16 + (lane & 15);
    int k = kk * 32 + (lane >> 4) * 8 + i;
    float w = W[(size_t)layer * 32768 + c * 256 + k];
    unsigned short h = f2bf(w);
    hi[idx] = h; lo[idx] = f2bf(w - bf2f(h));
}

__global__ void prep_mlp(const float* __restrict__ W1, const float* __restrict__ W2,
                         const float* __restrict__ W3,
                         unsigned short* w1h, unsigned short* w1l,
                         unsigned short* w2h, unsigned short* w2l,
                         unsigned short* w3h, unsigned short* w3l){
    int idx = blockIdx.x * blockDim.x + threadIdx.x;
    if (idx >= 73728) return;
    const float* W; unsigned short *ph, *pl; int NT, Kld, nc, local;
    if (idx < 32768)      { local = idx;         W = W1; ph = w1h; pl = w1l; NT = 16; Kld = 128; nc = 256; }
    else if (idx < 65536) { local = idx - 32768; W = W2; ph = w2h; pl = w2l; NT = 8;  Kld = 256; nc = 128; }
    else                  { local = idx - 65536; W = W3; ph = w3h; pl = w3l; NT = 4;  Kld = 128; nc = 63;  }
    int i = local & 7, lane = (local >> 3) & 63, nt = (local >> 9) % NT, kk = local / (512 * NT);
    int c = nt * 16 + (lane & 15);
    int k = kk * 32 + (lane >> 4) * 8 + i;
    float w = (c < nc) ? W[c * Kld + k] : 0.f;
    unsigned short h = f2bf(w);
    ph[local] = h; pl[local] = f2bf(w - bf2f(h));
}

// ================= GEMM core (split bf16, 3-MFMA) =================
template<int KK1, int KK2, int NT, int MT>
__device__ __forceinline__ void gemm_core(
    const unsigned short* __restrict__ A1h, const unsigned short* __restrict__ A1l,
    const unsigned short* __restrict__ A2h, const unsigned short* __restrict__ A2l,
    const unsigned short* __restrict__ Bh,  const unsigned short* __restrict__ Bl,
    int NTtot, int nt0, int waveRow0, int lane, f32x4 (&acc)[MT][NT])
{
    const int lm = lane & 15;
    const int lk = (lane >> 4) * 8;
#pragma unroll
    for (int kk = 0; kk < KK1 + KK2; ++kk){
        const unsigned short* ah; const unsigned short* al; int ld, kc;
        if (kk < KK1){ ah = A1h; al = A1l; ld = KK1 * 32; kc = kk * 32 + lk; }
        else         { ah = A2h; al = A2l; ld = KK2 * 32; kc = (kk - KK1) * 32 + lk; }
        s16x8 Ah[MT], Al[MT];
#pragma unroll
        for (int mi = 0; mi < MT; ++mi){
            size_t base = (size_t)(waveRow0 + mi * 16 + lm) * ld + kc;   // unguarded: OOB rows masked at store
            Ah[mi] = *reinterpret_cast<const s16x8*>(ah + base);
            Al[mi] = *reinterpret_cast<const s16x8*>(al + base);
        }
        const unsigned short* bp = Bh + ((size_t)(kk * NTtot + nt0)) * 512 + lane * 8;
        const unsigned short* bq = Bl + ((size_t)(kk * NTtot + nt0)) * 512 + lane * 8;
#pragma unroll
        for (int nt = 0; nt < NT; ++nt){
            s16x8 bh = *reinterpret_cast<const s16x8*>(bp + nt * 512);
            s16x8 bl = *reinterpret_cast<const s16x8*>(bq + nt * 512);
#pragma unroll
            for (int mi = 0; mi < MT; ++mi){
                acc[mi][nt] = __builtin_amdgcn_mfma_f32_16x16x32_bf16(Ah[mi], bh, acc[mi][nt], 0, 0, 0);
                acc[mi][nt] = __builtin_amdgcn_mfma_f32_16x16x32_bf16(Ah[mi], bl, acc[mi][nt], 0, 0, 0);
                acc[mi][nt] = __builtin_amdgcn_mfma_f32_16x16x32_bf16(Al[mi], bh, acc[mi][nt], 0, 0, 0);
            }
        }
    }
}

// epilogue: C/D layout col=lane&15, row=(lane>>4)*4+j
template<int NT, int MT, int ACT, bool HAS_BIAS, bool SPLITOUT>
__device__ __forceinline__ void epilogue(
    f32x4 (&acc)[MT][NT], const float* __restrict__ bias, int nt0,
    int waveRow0, int ldc, int ncols,
    unsigned short* __restrict__ Ch, unsigned short* __restrict__ Cl,
    float* __restrict__ Cf, int lane)
{
    const int lm = lane & 15;
    const int cr = (lane >> 4) * 4;
#pragma unroll
    for (int mi = 0; mi < MT; ++mi){
        int r0 = waveRow0 + mi * 16 + cr;
#pragma unroll
        for (int nt = 0; nt < NT; ++nt){
            int col = (nt0 + nt) * 16 + lm;
            if (col >= ncols) continue;
            float bv = HAS_BIAS ? bias[col] : 0.f;
#pragma unroll
            for (int j = 0; j < 4; ++j){
                int row = r0 + j;
                if (row >= NN) continue;
                float v = acc[mi][nt][j] + bv;
                if (ACT == 1) v = v > 0.f ? v : 0.f;
                else if (ACT == 2) v = tanhf(v);
                if (SPLITOUT){
                    unsigned short h = f2bf(v);
                    unsigned short l = f2bf(v - bf2f(h));
                    Ch[(size_t)row * ldc + col] = h;
                    Cl[(size_t)row * ldc + col] = l;
                } else {
                    Cf[(size_t)row * ldc + col] = v;
                }
            }
        }
    }
}

template<int KK1, int KK2, int NT, int MT, int ACT, bool HAS_BIAS, bool SPLITOUT>
__global__ __launch_bounds__(256) void gemm_split(
    const unsigned short* __restrict__ A1h, const unsigned short* __restrict__ A1l,
    const unsigned short* __restrict__ A2h, const unsigned short* __restrict__ A2l,
    const unsigned short* __restrict__ Bh,  const unsigned short* __restrict__ Bl, int NTtot,
    const float* __restrict__ bias,
    unsigned short* __restrict__ Ch, unsigned short* __restrict__ Cl, float* __restrict__ Cf,
    int ldc, int ncols)
{
    const int lane = threadIdx.x & 63;
    const int w    = threadIdx.x >> 6;
    const int nt0  = blockIdx.y * NT;
    const int waveRow0 = blockIdx.x * (MT * 64) + w * (MT * 16);
    f32x4 acc[MT][NT];
#pragma unroll
    for (int mi = 0; mi < MT; ++mi)
#pragma unroll
        for (int nt = 0; nt < NT; ++nt)
#pragma unroll
            for (int j = 0; j < 4; ++j) acc[mi][nt][j] = 0.f;
    gemm_core<KK1, KK2, NT, MT>(A1h, A1l, A2h, A2l, Bh, Bl, NTtot, nt0, waveRow0, lane, acc);
    epilogue<NT, MT, ACT, HAS_BIAS, SPLITOUT>(acc, bias, nt0, waveRow0, ldc, ncols, Ch, Cl, Cf, lane);
}

// fused: h_next = relu([aggr|h] Wu^T)  (write) ; m_next = tanh(h_next Wm^T + bm) (write)
template<bool WITH_MSG>
__global__ __launch_bounds__(256) void fused_update_msg(
    const unsigned short* __restrict__ agh, const unsigned short* __restrict__ agl,
    const unsigned short* __restrict__ hh,  const unsigned short* __restrict__ hl,
    const unsigned short* __restrict__ Wuh, const unsigned short* __restrict__ Wul,
    const unsigned short* __restrict__ Wmh, const unsigned short* __restrict__ Wml,
    const float* __restrict__ bm,
    unsigned short* __restrict__ oh, unsigned short* __restrict__ ol,
    unsigned short* __restrict__ mh, unsigned short* __restrict__ ml)
{
    const int lane = threadIdx.x & 63;
    const int w    = threadIdx.x >> 6;
    const int waveRow0 = blockIdx.x * 128 + w * 32;
    f32x4 acc[2][8];
#pragma unroll
    for (int mi = 0; mi < 2; ++mi)
#pragma unroll
        for (int nt = 0; nt < 8; ++nt)
#pragma unroll
            for (int j = 0; j < 4; ++j) acc[mi][nt][j] = 0.f;
    gemm_core<4, 4, 8, 2>(agh, agl, hh, hl, Wuh, Wul, 8, 0, waveRow0, lane, acc);
    epilogue<8, 2, 1, false, true>(acc, nullptr, 0, waveRow0, 128, 128, oh, ol, nullptr, lane);
    if (WITH_MSG){
        __syncthreads();   // drain stores; phase 2 re-reads freshly-written L1/L2-hot h rows
        f32x4 acc2[2][8];
#pragma unroll
        for (int mi = 0; mi < 2; ++mi)
#pragma unroll
            for (int nt = 0; nt < 8; ++nt)
#pragma unroll
                for (int j = 0; j < 4; ++j) acc2[mi][nt][j] = 0.f;
        gemm_core<4, 0, 8, 2>(oh, ol, nullptr, nullptr, Wmh, Wml, 8, 0, waveRow0, lane, acc2);
        epilogue<8, 2, 2, true, true>(acc2, bm, 0, waveRow0, 128, 128, mh, ml, nullptr, lane);
    }
}

// ================= aggregation: aggr[n] = m[n] + sum m[src] (hi/lo pairs) =================
__global__ __launch_bounds__(256) void aggregate_kernel(
    const unsigned short* __restrict__ mh, const unsigned short* __restrict__ ml,
    const int* __restrict__ row_start, const int* __restrict__ cols,
    unsigned short* __restrict__ ah, unsigned short* __restrict__ al)
{
    int wid  = (blockIdx.x * 256 + threadIdx.x) >> 6;
    int lane = threadIdx.x & 63;
    if (wid >= NN) return;
    int s0 = row_start[wid], s1 = row_start[wid + 1];
    const unsigned* mh32 = (const unsigned*)mh;
    const unsigned* ml32 = (const unsigned*)ml;
    size_t self = (size_t)wid * 64 + lane;          // uint units; row = 64 uints
    unsigned hv = mh32[self], lv = ml32[self];
    float a0 = bf2f((unsigned short)hv) + bf2f((unsigned short)lv);
    float a1 = bf2f((unsigned short)(hv >> 16)) + bf2f((unsigned short)(lv >> 16));
    for (int e = s0; e < s1; ++e){
        int s = cols[e];
        unsigned h2 = mh32[(size_t)s * 64 + lane];
        unsigned l2 = ml32[(size_t)s * 64 + lane];
        a0 += bf2f((unsigned short)h2) + bf2f((unsigned short)l2);
        a1 += bf2f((unsigned short)(h2 >> 16)) + bf2f((unsigned short)(l2 >> 16));
    }
    unsigned short h0 = f2bf(a0), l0 = f2bf(a0 - bf2f(h0));
    unsigned short h1 = f2bf(a1), l1 = f2bf(a1 - bf2f(h1));
    ((unsigned*)ah)[self] = (unsigned)h0 | ((unsigned)h1 << 16);
    ((unsigned*)al)[self] = (unsigned)l0 | ((unsigned)l1 << 16);
}

// ================= host =================
extern "C" void kernel_launch(void* const* d_in, const int* in_sizes, int n_in,
                              void* d_out, int out_size, void* d_ws, size_t ws_size,
                              hipStream_t stream)
{
    const float* x     = (const float*)d_in[0];
    const int*   ei    = (const int*)d_in[1];
    const float* W_msg = (const float*)d_in[3];
    const float* b_msg = (const float*)d_in[4];
    const float* W_upd = (const float*)d_in[5];
    const float* W1    = (const float*)d_in[6];
    const float* b1    = (const float*)d_in[7];
    const float* W2    = (const float*)d_in[8];
    const float* b2    = (const float*)d_in[9];
    const float* W3    = (const float*)d_in[10];
    const float* b3    = (const float*)d_in[11];
    const int* srcp = ei;
    const int* dstp = ei + NE;

    char* ws = (char*)d_ws;
    size_t off = 0;
    auto carve = [&](size_t bytes) -> void* {
        void* p = ws + off;
        off += (bytes + 255) & ~(size_t)255;
        return p;
    };
    const size_t PAIR = (size_t)NN * 128 * 2;   // 12.8 MB, multiple of 256
    unsigned short* xh  = (unsigned short*)carve(PAIR);   // xh,xl adjacent -> h1_hi overlay
    unsigned short* xl  = (unsigned short*)carve(PAIR);
    unsigned short* hAh = (unsigned short*)carve(PAIR);
    unsigned short* hAl = (unsigned short*)carve(PAIR);
    unsigned short* mh  = (unsigned short*)carve(PAIR);   // mh,ml adjacent -> h1_lo overlay
    unsigned short* ml  = (unsigned short*)carve(PAIR);
    unsigned short* agh = (unsigned short*)carve(PAIR);
    unsigned short* agl = (unsigned short*)carve(PAIR);

    int* counts    = (int*)carve((size_t)NN * 4);
    int* cursor    = (int*)carve((size_t)NN * 4);
    int* row_start = (int*)carve(((size_t)NN + 1) * 4);
    int* bsum      = (int*)carve(256 * 4);
    int* boff      = (int*)carve(256 * 4);
    int* colv      = (int*)carve((size_t)NE * 4);

    unsigned short* wmsg_hi = (unsigned short*)carve((size_t)21 * 16384 * 2);
    unsigned short* wmsg_lo = (unsigned short*)carve((size_t)21 * 16384 * 2);
    unsigned short* wupd_hi = (unsigned short*)carve((size_t)21 * 32768 * 2);
    unsigned short* wupd_lo = (unsigned short*)carve((size_t)21 * 32768 * 2);
    unsigned short* w1_hi   = (unsigned short*)carve(32768 * 2);
    unsigned short* w1_lo   = (unsigned short*)carve(32768 * 2);
    unsigned short* w2_hi   = (unsigned short*)carve(32768 * 2);
    unsigned short* w2_lo   = (unsigned short*)carve(32768 * 2);
    unsigned short* w3_hi   = (unsigned short*)carve(8192 * 2);
    unsigned short* w3_lo   = (unsigned short*)carve(8192 * 2);
    (void)carve(65536);   // tail pad: unguarded A-loads may overrun by <24 KB

    const int NB = (NN + 255) / 256;   // 196

    // CSR
    hipMemsetAsync(counts, 0, (size_t)NN * 4, stream);
    hist_kernel<<<(NE + 255) / 256, 256, 0, stream>>>(dstp, counts);
    blocksum_kernel<<<NB, 256, 0, stream>>>(counts, bsum);
    scanb_kernel<<<1, 256, 0, stream>>>(bsum, boff, row_start, NB);
    localscan_kernel<<<NB, 256, 0, stream>>>(counts, boff, row_start, cursor);
    scatter_kernel<<<(NE + 255) / 256, 256, 0, stream>>>(srcp, dstp, cursor, colv);

    // prep
    convert_x_kernel<<<(NN * 128 / 4 + 255) / 256, 256, 0, stream>>>(x, xh, xl);
    prep_wmsg<<<(21 * 16384 + 255) / 256, 256, 0, stream>>>(W_msg, wmsg_hi, wmsg_lo);
    prep_wupd<<<(21 * 32768 + 255) / 256, 256, 0, stream>>>(W_upd, wupd_hi, wupd_lo);
    prep_mlp<<<288, 256, 0, stream>>>(W1, W2, W3, w1_hi, w1_lo, w2_hi, w2_lo, w3_hi, w3_lo);

    const int GB = (NN + 127) / 128;   // 391 blocks (MT=2, 4 waves)

    // m_0 = tanh(x Wm_0^T + bm_0)
    gemm_split<4, 0, 8, 2, 2, true, true><<<GB, 256, 0, stream>>>(
        xh, xl, nullptr, nullptr, wmsg_hi, wmsg_lo, 8, b_msg, mh, ml, nullptr, 128, 128);

    // 21 layers: aggregate then fused update(+next msg); h ping-pongs x-region <-> hA
    const unsigned short* ch = xh; const unsigned short* cl = xl;
    unsigned short* oh = hAh;      unsigned short* ol = hAl;
    for (int l = 0; l < 21; ++l){
        aggregate_kernel<<<(NN * 64 + 255) / 256, 256, 0, stream>>>(mh, ml, row_start, colv, agh, agl);
        if (l < 20){
            fused_update_msg<true><<<GB, 256, 0, stream>>>(
                agh, agl, ch, cl,
                wupd_hi + (size_t)l * 32768, wupd_lo + (size_t)l * 32768,
                wmsg_hi + (size_t)(l + 1) * 16384, wmsg_lo + (size_t)(l + 1) * 16384,
                b_msg + (size_t)(l + 1) * 128,
                oh, ol, mh, ml);
        } else {
            fused_update_msg<false><<<GB, 256, 0, stream>>>(
                agh, agl, ch, cl,
                wupd_hi + (size_t)l * 32768, wupd_lo + (size_t)l * 32768,
                nullptr, nullptr, nullptr,
                oh, ol, nullptr, nullptr);
        }
        const unsigned short* th = ch; const unsigned short* tl = cl;
        ch = oh; cl = ol;
        oh = (unsigned short*)th; ol = (unsigned short*)tl;
    }
    // h_21 now in (ch,cl) == hA pair (21 swaps, odd)

    // MLP head. h1 overlays x-region(hi) + m-region(lo); h2 overlays aggr pair.
    unsigned short* h1h = xh;   // spans xh+xl  (N x 256 ushorts)
    unsigned short* h1l = mh;   // spans mh+ml
    unsigned short* h2h = agh;
    unsigned short* h2l = agl;
    gemm_split<4, 0, 8, 2, 1, true, true><<<dim3(GB, 2), 256, 0, stream>>>(
        ch, cl, nullptr, nullptr, w1_hi, w1_lo, 16, b1, h1h, h1l, nullptr, 256, 256);
    gemm_split<8, 0, 8, 2, 1, true, true><<<GB, 256, 0, stream>>>(
        h1h, h1l, nullptr, nullptr, w2_hi, w2_lo, 8, b2, h2h, h2l, nullptr, 128, 128);
    gemm_split<4, 0, 4, 2, 0, true, false><<<GB, 256, 0, stream>>>(
        h2h, h2l, nullptr, nullptr, w3_hi, w3_lo, 4, b3, nullptr, nullptr, (float*)d_out, 63, 63);
}

// Round 4
// 2263.430 us; speedup vs baseline: 1.5939x; 1.3836x over previous
//
#include <hip/hip_runtime.h>
#include <cstdint>

#define NN 50000
#define NE 800000

typedef __attribute__((ext_vector_type(8))) short  s16x8;
typedef __attribute__((ext_vector_type(4))) float  f32x4;
typedef __attribute__((ext_vector_type(4))) unsigned short u16x4;

__device__ __forceinline__ unsigned short f2bf(float f){
    unsigned u = __float_as_uint(f);
    return (unsigned short)((u + 0x7fffu + ((u >> 16) & 1u)) >> 16);   // RNE
}
__device__ __forceinline__ float bf2f(unsigned short b){ return __uint_as_float(((unsigned)b) << 16); }
__device__ __forceinline__ unsigned short f2h(float v){
    _Float16 f = (_Float16)v; unsigned short u; __builtin_memcpy(&u, &f, 2); return u;
}
__device__ __forceinline__ float h2f(unsigned short u){
    _Float16 f; __builtin_memcpy(&f, &u, 2); return (float)f;
}

// ================= CSR build =================
__global__ void hist_kernel(const int* __restrict__ dst, int* counts){
    int e = blockIdx.x * blockDim.x + threadIdx.x;
    if (e < NE) atomicAdd(&counts[dst[e]], 1);
}

__global__ void blocksum_kernel(const int* __restrict__ counts, int* __restrict__ bsum){
    __shared__ int sd[256];
    int i = blockIdx.x * 256 + threadIdx.x;
    int c = (i < NN) ? counts[i] : 0;
    sd[threadIdx.x] = c; __syncthreads();
    for (int o = 128; o > 0; o >>= 1){
        if (threadIdx.x < o) sd[threadIdx.x] += sd[threadIdx.x + o];
        __syncthreads();
    }
    if (threadIdx.x == 0) bsum[blockIdx.x] = sd[0];
}

__global__ void scanb_kernel(const int* __restrict__ bsum, int* __restrict__ boff,
                             int* __restrict__ row_start, int nb){
    __shared__ int sd[256];
    int t = threadIdx.x;
    int v = (t < nb) ? bsum[t] : 0;
    sd[t] = v; __syncthreads();
    for (int o = 1; o < 256; o <<= 1){
        int u = (t >= o) ? sd[t - o] : 0;
        __syncthreads();
        sd[t] += u;
        __syncthreads();
    }
    if (t < nb) boff[t] = sd[t] - v;   // exclusive
    if (t == 0) row_start[NN] = NE;
}

__global__ void localscan_kernel(const int* __restrict__ counts, const int* __restrict__ boff,
                                 int* __restrict__ row_start, int* __restrict__ cursor){
    __shared__ int sd[256];
    int t = threadIdx.x, i = blockIdx.x * 256 + t;
    int c = (i < NN) ? counts[i] : 0;
    sd[t] = c; __syncthreads();
    for (int o = 1; o < 256; o <<= 1){
        int u = (t >= o) ? sd[t - o] : 0;
        __syncthreads();
        sd[t] += u;
        __syncthreads();
    }
    if (i < NN){
        int ex = boff[blockIdx.x] + sd[t] - c;
        row_start[i] = ex; cursor[i] = ex;
    }
}

__global__ void scatter_kernel(const int* __restrict__ src, const int* __restrict__ dst,
                               int* cursor, int* __restrict__ colv){
    int e = blockIdx.x * blockDim.x + threadIdx.x;
    if (e < NE){
        int pos = atomicAdd(&cursor[dst[e]], 1);
        colv[pos] = src[e];
    }
}

// ================= x -> hi/lo =================
__global__ void convert_x_kernel(const float* __restrict__ x,
                                 unsigned short* __restrict__ xh, unsigned short* __restrict__ xl){
    int i = blockIdx.x * blockDim.x + threadIdx.x;
    if (i >= NN * 128 / 4) return;
    f32x4 v = *reinterpret_cast<const f32x4*>(x + (size_t)i * 4);
    u16x4 h, l;
#pragma unroll
    for (int j = 0; j < 4; ++j){
        unsigned short hh = f2bf(v[j]);
        h[j] = hh;
        l[j] = f2bf(v[j] - bf2f(hh));
    }
    *reinterpret_cast<u16x4*>(xh + (size_t)i * 4) = h;
    *reinterpret_cast<u16x4*>(xl + (size_t)i * 4) = l;
}

// ================= weight prep (fp32 -> frag-linear bf16 hi/lo) =================
// frag value = W[nt*16+(lane&15)][kk*32+(lane>>4)*8+i], flat [kk][nt][lane][i]
__global__ void prep_wmsg(const float* __restrict__ W, unsigned short* __restrict__ hi,
                          unsigned short* __restrict__ lo){
    int idx = blockIdx.x * blockDim.x + threadIdx.x;
    const int per = 4 * 8 * 512;
    if (idx >= 21 * per) return;
    int layer = idx / per, r = idx % per;
    int kk = r / 4096, nt = (r / 512) & 7, lane = (r / 8) & 63, i = r & 7;
    int c = nt * 16 + (lane & 15);
    int k = kk * 32 + (lane >> 4) * 8 + i;
    float w = W[(size_t)layer * 16384 + c * 128 + k];
    unsigned short h = f2bf(w);
    hi[idx] = h; lo[idx] = f2bf(w - bf2f(h));
}

__global__ void prep_wupd(const float* __restrict__ W, unsigned short* __restrict__ hi,
                          unsigned short* __restrict__ lo){
    int idx = blockIdx.x * blockDim.x + threadIdx.x;
    const int per = 8 * 8 * 512;
    if (idx >= 21 * per) return;
    int layer = idx / per, r = idx % per;
    int kk = r / 4096, nt = (r / 512) & 7, lane = (r / 8) & 63, i = r & 7;
    int c = nt * 16 + (lane & 15);
    int k = kk * 32 + (lane >> 4) * 8 + i;
    float w = W[(size_t)layer * 32768 + c * 256 + k];
    unsigned short h = f2bf(w);
    hi[idx] = h; lo[idx] = f2bf(w - bf2f(h));
}

__global__ void prep_mlp(const float* __restrict__ W1, const float* __restrict__ W2,
                         const float* __restrict__ W3,
                         unsigned short* w1h, unsigned short* w1l,
                         unsigned short* w2h, unsigned short* w2l,
                         unsigned short* w3h, unsigned short* w3l){
    int idx = blockIdx.x * blockDim.x + threadIdx.x;
    if (idx >= 73728) return;
    const float* W; unsigned short *ph, *pl; int NT, Kld, nc, local;
    if (idx < 32768)      { local = idx;         W = W1; ph = w1h; pl = w1l; NT = 16; Kld = 128; nc = 256; }
    else if (idx < 65536) { local = idx - 32768; W = W2; ph = w2h; pl = w2l; NT = 8;  Kld = 256; nc = 128; }
    else                  { local = idx - 65536; W = W3; ph = w3h; pl = w3l; NT = 4;  Kld = 128; nc = 63;  }
    int i = local & 7, lane = (local >> 3) & 63, nt = (local >> 9) % NT, kk = local / (512 * NT);
    int c = nt * 16 + (lane & 15);
    int k = kk * 32 + (lane >> 4) * 8 + i;
    float w = (c < nc) ? W[c * Kld + k] : 0.f;
    unsigned short h = f2bf(w);
    ph[local] = h; pl[local] = f2bf(w - bf2f(h));
}

// ================= GEMM core (split bf16, 3-MFMA) =================
template<int KK1, int KK2, int NT, int MT>
__device__ __forceinline__ void gemm_core(
    const unsigned short* __restrict__ A1h, const unsigned short* __restrict__ A1l,
    const unsigned short* __restrict__ A2h, const unsigned short* __restrict__ A2l,
    const unsigned short* __restrict__ Bh,  const unsigned short* __restrict__ Bl,
    int NTtot, int nt0, int waveRow0, int lane, f32x4 (&acc)[MT][NT])
{
    const int lm = lane & 15;
    const int lk = (lane >> 4) * 8;
#pragma unroll
    for (int kk = 0; kk < KK1 + KK2; ++kk){
        const unsigned short* ah; const unsigned short* al; int ld, kc;
        if (kk < KK1){ ah = A1h; al = A1l; ld = KK1 * 32; kc = kk * 32 + lk; }
        else         { ah = A2h; al = A2l; ld = KK2 * 32; kc = (kk - KK1) * 32 + lk; }
        s16x8 Ah[MT], Al[MT];
#pragma unroll
        for (int mi = 0; mi < MT; ++mi){
            size_t base = (size_t)(waveRow0 + mi * 16 + lm) * ld + kc;   // unguarded: OOB rows masked at store
            Ah[mi] = *reinterpret_cast<const s16x8*>(ah + base);
            Al[mi] = *reinterpret_cast<const s16x8*>(al + base);
        }
        const unsigned short* bp = Bh + ((size_t)(kk * NTtot + nt0)) * 512 + lane * 8;
        const unsigned short* bq = Bl + ((size_t)(kk * NTtot + nt0)) * 512 + lane * 8;
#pragma unroll
        for (int nt = 0; nt < NT; ++nt){
            s16x8 bh = *reinterpret_cast<const s16x8*>(bp + nt * 512);
            s16x8 bl = *reinterpret_cast<const s16x8*>(bq + nt * 512);
#pragma unroll
            for (int mi = 0; mi < MT; ++mi){
                acc[mi][nt] = __builtin_amdgcn_mfma_f32_16x16x32_bf16(Ah[mi], bh, acc[mi][nt], 0, 0, 0);
                acc[mi][nt] = __builtin_amdgcn_mfma_f32_16x16x32_bf16(Ah[mi], bl, acc[mi][nt], 0, 0, 0);
                acc[mi][nt] = __builtin_amdgcn_mfma_f32_16x16x32_bf16(Al[mi], bh, acc[mi][nt], 0, 0, 0);
            }
        }
    }
}

// epilogue: C/D layout col=lane&15, row=(lane>>4)*4+j
// OUTMODE: 0 = fp32 (Cf), 1 = bf16 hi/lo pair (Ch,Cl), 2 = fp16 (Ch)
template<int NT, int MT, int ACT, bool HAS_BIAS, int OUTMODE>
__device__ __forceinline__ void epilogue(
    f32x4 (&acc)[MT][NT], const float* __restrict__ bias, int nt0,
    int waveRow0, int ldc, int ncols,
    unsigned short* __restrict__ Ch, unsigned short* __restrict__ Cl,
    float* __restrict__ Cf, int lane)
{
    const int lm = lane & 15;
    const int cr = (lane >> 4) * 4;
#pragma unroll
    for (int mi = 0; mi < MT; ++mi){
        int r0 = waveRow0 + mi * 16 + cr;
#pragma unroll
        for (int nt = 0; nt < NT; ++nt){
            int col = (nt0 + nt) * 16 + lm;
            if (col >= ncols) continue;
            float bv = HAS_BIAS ? bias[col] : 0.f;
#pragma unroll
            for (int j = 0; j < 4; ++j){
                int row = r0 + j;
                if (row >= NN) continue;
                float v = acc[mi][nt][j] + bv;
                if (ACT == 1) v = v > 0.f ? v : 0.f;
                else if (ACT == 2) v = tanhf(v);
                if (OUTMODE == 1){
                    unsigned short h = f2bf(v);
                    unsigned short l = f2bf(v - bf2f(h));
                    Ch[(size_t)row * ldc + col] = h;
                    Cl[(size_t)row * ldc + col] = l;
                } else if (OUTMODE == 2){
                    Ch[(size_t)row * ldc + col] = f2h(v);
                } else {
                    Cf[(size_t)row * ldc + col] = v;
                }
            }
        }
    }
}

template<int KK1, int KK2, int NT, int MT, int ACT, bool HAS_BIAS, int OUTMODE>
__global__ __launch_bounds__(256) void gemm_split(
    const unsigned short* __restrict__ A1h, const unsigned short* __restrict__ A1l,
    const unsigned short* __restrict__ A2h, const unsigned short* __restrict__ A2l,
    const unsigned short* __restrict__ Bh,  const unsigned short* __restrict__ Bl, int NTtot,
    const float* __restrict__ bias,
    unsigned short* __restrict__ Ch, unsigned short* __restrict__ Cl, float* __restrict__ Cf,
    int ldc, int ncols)
{
    const int lane = threadIdx.x & 63;
    const int w    = threadIdx.x >> 6;
    const int nt0  = blockIdx.y * NT;
    const int waveRow0 = blockIdx.x * (MT * 64) + w * (MT * 16);
    f32x4 acc[MT][NT];
#pragma unroll
    for (int mi = 0; mi < MT; ++mi)
#pragma unroll
        for (int nt = 0; nt < NT; ++nt)
#pragma unroll
            for (int j = 0; j < 4; ++j) acc[mi][nt][j] = 0.f;
    gemm_core<KK1, KK2, NT, MT>(A1h, A1l, A2h, A2l, Bh, Bl, NTtot, nt0, waveRow0, lane, acc);
    epilogue<NT, MT, ACT, HAS_BIAS, OUTMODE>(acc, bias, nt0, waveRow0, ldc, ncols, Ch, Cl, Cf, lane);
}

// fused: h' = relu([aggr|h] Wu^T) -> (oh,ol) hi/lo ; m' = tanh(h' Wm^T + bm) -> mf16
template<bool WITH_MSG>
__global__ __launch_bounds__(256) void fused_update_msg(
    const unsigned short* __restrict__ agh, const unsigned short* __restrict__ agl,
    const unsigned short* __restrict__ hh,  const unsigned short* __restrict__ hl,
    const unsigned short* __restrict__ Wuh, const unsigned short* __restrict__ Wul,
    const unsigned short* __restrict__ Wmh, const unsigned short* __restrict__ Wml,
    const float* __restrict__ bm,
    unsigned short* __restrict__ oh, unsigned short* __restrict__ ol,
    unsigned short* __restrict__ mf16)
{
    const int lane = threadIdx.x & 63;
    const int w    = threadIdx.x >> 6;
    const int waveRow0 = blockIdx.x * 128 + w * 32;
    f32x4 acc[2][8];
#pragma unroll
    for (int mi = 0; mi < 2; ++mi)
#pragma unroll
        for (int nt = 0; nt < 8; ++nt)
#pragma unroll
            for (int j = 0; j < 4; ++j) acc[mi][nt][j] = 0.f;
    gemm_core<4, 4, 8, 2>(agh, agl, hh, hl, Wuh, Wul, 8, 0, waveRow0, lane, acc);
    epilogue<8, 2, 1, false, 1>(acc, nullptr, 0, waveRow0, 128, 128, oh, ol, nullptr, lane);
    if (WITH_MSG){
        __syncthreads();   // drain stores; phase 2 re-reads this wave's freshly-written h rows
        f32x4 acc2[2][8];
#pragma unroll
        for (int mi = 0; mi < 2; ++mi)
#pragma unroll
            for (int nt = 0; nt < 8; ++nt)
#pragma unroll
                for (int j = 0; j < 4; ++j) acc2[mi][nt][j] = 0.f;
        gemm_core<4, 0, 8, 2>(oh, ol, nullptr, nullptr, Wmh, Wml, 8, 0, waveRow0, lane, acc2);
        epilogue<8, 2, 2, true, 2>(acc2, bm, 0, waveRow0, 128, 128, mf16, nullptr, nullptr, lane);
    }
}

// ================= aggregation: aggr[n] = m[n] + sum m[src]; fp16 gather -> bf16 hi/lo =================
__global__ __launch_bounds__(256) void aggregate_kernel(
    const unsigned short* __restrict__ mf16,
    const int* __restrict__ row_start, const int* __restrict__ cols,
    unsigned short* __restrict__ ah, unsigned short* __restrict__ al)
{
    int wid  = (blockIdx.x * 256 + threadIdx.x) >> 6;
    int lane = threadIdx.x & 63;
    if (wid >= NN) return;
    int s0 = row_start[wid], s1 = row_start[wid + 1];
    const unsigned* mp = (const unsigned*)mf16;           // row = 64 uints (2 fp16 each)
    size_t self = (size_t)wid * 64 + lane;
    unsigned v = mp[self];
    float a0 = h2f((unsigned short)v);
    float a1 = h2f((unsigned short)(v >> 16));
    int e = s0;
    for (; e + 1 < s1; e += 2){                           // 2 independent gathers in flight
        int sA = cols[e], sB = cols[e + 1];
        unsigned vA = mp[(size_t)sA * 64 + lane];
        unsigned vB = mp[(size_t)sB * 64 + lane];
        a0 += h2f((unsigned short)vA) + h2f((unsigned short)vB);
        a1 += h2f((unsigned short)(vA >> 16)) + h2f((unsigned short)(vB >> 16));
    }
    if (e < s1){
        unsigned vA = mp[(size_t)cols[e] * 64 + lane];
        a0 += h2f((unsigned short)vA);
        a1 += h2f((unsigned short)(vA >> 16));
    }
    unsigned short h0 = f2bf(a0), l0 = f2bf(a0 - bf2f(h0));
    unsigned short h1 = f2bf(a1), l1 = f2bf(a1 - bf2f(h1));
    ((unsigned*)ah)[self] = (unsigned)h0 | ((unsigned)h1 << 16);
    ((unsigned*)al)[self] = (unsigned)l0 | ((unsigned)l1 << 16);
}

// ================= host =================
extern "C" void kernel_launch(void* const* d_in, const int* in_sizes, int n_in,
                              void* d_out, int out_size, void* d_ws, size_t ws_size,
                              hipStream_t stream)
{
    const float* x     = (const float*)d_in[0];
    const int*   ei    = (const int*)d_in[1];
    const float* W_msg = (const float*)d_in[3];
    const float* b_msg = (const float*)d_in[4];
    const float* W_upd = (const float*)d_in[5];
    const float* W1    = (const float*)d_in[6];
    const float* b1    = (const float*)d_in[7];
    const float* W2    = (const float*)d_in[8];
    const float* b2    = (const float*)d_in[9];
    const float* W3    = (const float*)d_in[10];
    const float* b3    = (const float*)d_in[11];
    const int* srcp = ei;
    const int* dstp = ei + NE;

    char* ws = (char*)d_ws;
    size_t off = 0;
    auto carve = [&](size_t bytes) -> void* {
        void* p = ws + off;
        off += (bytes + 255) & ~(size_t)255;
        return p;
    };
    const size_t HALF = (size_t)NN * 128 * 2;   // 12.8 MB, multiple of 256
    // order matters for head overlays (all carves contiguous):
    unsigned short* xh   = (unsigned short*)carve(HALF);   // h1_hi spans xh+xl
    unsigned short* xl   = (unsigned short*)carve(HALF);
    unsigned short* hAh  = (unsigned short*)carve(HALF);   // h2 pair in head
    unsigned short* hAl  = (unsigned short*)carve(HALF);
    unsigned short* mf16 = (unsigned short*)carve(HALF);   // h1_lo spans mf16+agh
    unsigned short* agh  = (unsigned short*)carve(HALF);
    unsigned short* agl  = (unsigned short*)carve(HALF);

    int* counts    = (int*)carve((size_t)NN * 4);
    int* cursor    = (int*)carve((size_t)NN * 4);
    int* row_start = (int*)carve(((size_t)NN + 1) * 4);
    int* bsum      = (int*)carve(256 * 4);
    int* boff      = (int*)carve(256 * 4);
    int* colv      = (int*)carve((size_t)NE * 4);

    unsigned short* wmsg_hi = (unsigned short*)carve((size_t)21 * 16384 * 2);
    unsigned short* wmsg_lo = (unsigned short*)carve((size_t)21 * 16384 * 2);
    unsigned short* wupd_hi = (unsigned short*)carve((size_t)21 * 32768 * 2);
    unsigned short* wupd_lo = (unsigned short*)carve((size_t)21 * 32768 * 2);
    unsigned short* w1_hi   = (unsigned short*)carve(32768 * 2);
    unsigned short* w1_lo   = (unsigned short*)carve(32768 * 2);
    unsigned short* w2_hi   = (unsigned short*)carve(32768 * 2);
    unsigned short* w2_lo   = (unsigned short*)carve(32768 * 2);
    unsigned short* w3_hi   = (unsigned short*)carve(8192 * 2);
    unsigned short* w3_lo   = (unsigned short*)carve(8192 * 2);
    (void)carve(65536);   // tail pad: unguarded A-loads overrun < 25 KB

    const int NB = (NN + 255) / 256;   // 196

    // CSR
    hipMemsetAsync(counts, 0, (size_t)NN * 4, stream);
    hist_kernel<<<(NE + 255) / 256, 256, 0, stream>>>(dstp, counts);
    blocksum_kernel<<<NB, 256, 0, stream>>>(counts, bsum);
    scanb_kernel<<<1, 256, 0, stream>>>(bsum, boff, row_start, NB);
    localscan_kernel<<<NB, 256, 0, stream>>>(counts, boff, row_start, cursor);
    scatter_kernel<<<(NE + 255) / 256, 256, 0, stream>>>(srcp, dstp, cursor, colv);

    // prep
    convert_x_kernel<<<(NN * 128 / 4 + 255) / 256, 256, 0, stream>>>(x, xh, xl);
    prep_wmsg<<<(21 * 16384 + 255) / 256, 256, 0, stream>>>(W_msg, wmsg_hi, wmsg_lo);
    prep_wupd<<<(21 * 32768 + 255) / 256, 256, 0, stream>>>(W_upd, wupd_hi, wupd_lo);
    prep_mlp<<<288, 256, 0, stream>>>(W1, W2, W3, w1_hi, w1_lo, w2_hi, w2_lo, w3_hi, w3_lo);

    const int GB = (NN + 127) / 128;   // 391 blocks (MT=2, 4 waves)

    // m_0 = tanh(x Wm_0^T + bm_0) -> fp16
    gemm_split<4, 0, 8, 2, 2, true, 2><<<GB, 256, 0, stream>>>(
        xh, xl, nullptr, nullptr, wmsg_hi, wmsg_lo, 8, b_msg, mf16, nullptr, nullptr, 128, 128);

    // 21 layers; h ping-pongs x pair <-> hA pair
    const unsigned short* ch = xh; const unsigned short* cl = xl;
    unsigned short* oh = hAh;      unsigned short* ol = hAl;
    for (int l = 0; l < 21; ++l){
        aggregate_kernel<<<(NN * 64 + 255) / 256, 256, 0, stream>>>(mf16, row_start, colv, agh, agl);
        if (l < 20){
            fused_update_msg<true><<<GB, 256, 0, stream>>>(
                agh, agl, ch, cl,
                wupd_hi + (size_t)l * 32768, wupd_lo + (size_t)l * 32768,
                wmsg_hi + (size_t)(l + 1) * 16384, wmsg_lo + (size_t)(l + 1) * 16384,
                b_msg + (size_t)(l + 1) * 128,
                oh, ol, mf16);
        } else {
            fused_update_msg<false><<<GB, 256, 0, stream>>>(
                agh, agl, ch, cl,
                wupd_hi + (size_t)l * 32768, wupd_lo + (size_t)l * 32768,
                nullptr, nullptr, nullptr,
                oh, ol, nullptr);
        }
        const unsigned short* th = ch; const unsigned short* tl = cl;
        ch = oh; cl = ol;
        oh = (unsigned short*)th; ol = (unsigned short*)tl;
    }
    // h_21 in (ch,cl) == hA pair (21 swaps)

    // MLP head overlays: h1_hi = xh..xl span, h1_lo = mf16..agh span, h2 = hA pair
    unsigned short* h1h = xh;
    unsigned short* h1l = mf16;
    gemm_split<4, 0, 8, 2, 1, true, 1><<<dim3(GB, 2), 256, 0, stream>>>(
        ch, cl, nullptr, nullptr, w1_hi, w1_lo, 16, b1, h1h, h1l, nullptr, 256, 256);
    gemm_split<8, 0, 8, 2, 1, true, 1><<<GB, 256, 0, stream>>>(
        h1h, h1l, nullptr, nullptr, w2_hi, w2_lo, 8, b2, hAh, hAl, nullptr, 128, 128);
    gemm_split<4, 0, 4, 2, 0, true, 0><<<GB, 256, 0, stream>>>(
        hAh, hAl, nullptr, nullptr, w3_hi, w3_lo, 4, b3, nullptr, nullptr, (float*)d_out, 63, 63);
}

// Round 5
// 1664.035 us; speedup vs baseline: 2.1680x; 1.3602x over previous
//
#include <hip/hip_runtime.h>
#include <cstdint>

#define NN 50000
#define NE 800000

typedef __attribute__((ext_vector_type(8))) short    s16x8;
typedef __attribute__((ext_vector_type(4))) float    f32x4;
typedef __attribute__((ext_vector_type(8))) float    f32x8;
typedef __attribute__((ext_vector_type(4))) unsigned short u16x4;
typedef _Float16 f16x8 __attribute__((ext_vector_type(8)));

typedef unsigned short ushort_t;
typedef unsigned int   uint_t;

__device__ __forceinline__ unsigned short f2h(float v){
    _Float16 f = (_Float16)v; unsigned short u; __builtin_memcpy(&u, &f, 2); return u;
}
__device__ __forceinline__ float h2f(unsigned short u){
    _Float16 f; __builtin_memcpy(&f, &u, 2); return (float)f;
}

// ================= CSR build =================
__global__ void hist_kernel(const int* __restrict__ dst, int* counts){
    int e = blockIdx.x * blockDim.x + threadIdx.x;
    if (e < NE) atomicAdd(&counts[dst[e]], 1);
}

__global__ void blocksum_kernel(const int* __restrict__ counts, int* __restrict__ bsum){
    __shared__ int sd[256];
    int i = blockIdx.x * 256 + threadIdx.x;
    int c = (i < NN) ? counts[i] : 0;
    sd[threadIdx.x] = c; __syncthreads();
    for (int o = 128; o > 0; o >>= 1){
        if (threadIdx.x < o) sd[threadIdx.x] += sd[threadIdx.x + o];
        __syncthreads();
    }
    if (threadIdx.x == 0) bsum[blockIdx.x] = sd[0];
}

__global__ void scanb_kernel(const int* __restrict__ bsum, int* __restrict__ boff,
                             int* __restrict__ row_start, int nb){
    __shared__ int sd[256];
    int t = threadIdx.x;
    int v = (t < nb) ? bsum[t] : 0;
    sd[t] = v; __syncthreads();
    for (int o = 1; o < 256; o <<= 1){
        int u = (t >= o) ? sd[t - o] : 0;
        __syncthreads();
        sd[t] += u;
        __syncthreads();
    }
    if (t < nb) boff[t] = sd[t] - v;   // exclusive
    if (t == 0) row_start[NN] = NE;
}

__global__ void localscan_kernel(const int* __restrict__ counts, const int* __restrict__ boff,
                                 int* __restrict__ row_start, int* __restrict__ cursor){
    __shared__ int sd[256];
    int t = threadIdx.x, i = blockIdx.x * 256 + t;
    int c = (i < NN) ? counts[i] : 0;
    sd[t] = c; __syncthreads();
    for (int o = 1; o < 256; o <<= 1){
        int u = (t >= o) ? sd[t - o] : 0;
        __syncthreads();
        sd[t] += u;
        __syncthreads();
    }
    if (i < NN){
        int ex = boff[blockIdx.x] + sd[t] - c;
        row_start[i] = ex; cursor[i] = ex;
    }
}

__global__ void scatter_kernel(const int* __restrict__ src, const int* __restrict__ dst,
                               int* cursor, int* __restrict__ colv){
    int e = blockIdx.x * blockDim.x + threadIdx.x;
    if (e < NE){
        int pos = atomicAdd(&cursor[dst[e]], 1);
        colv[pos] = src[e];
    }
}

// ================= x (fp32) -> fp16 =================
__global__ void convert_x_kernel(const float* __restrict__ x, ushort_t* __restrict__ xf){
    int i = blockIdx.x * blockDim.x + threadIdx.x;
    if (i >= NN * 32) return;           // NN*128/4
    f32x4 v = *reinterpret_cast<const f32x4*>(x + (size_t)i * 4);
    u16x4 h;
#pragma unroll
    for (int j = 0; j < 4; ++j) h[j] = f2h(v[j]);
    *reinterpret_cast<u16x4*>(xf + (size_t)i * 4) = h;
}

// ================= weight prep (fp32 -> frag-linear fp16 hi/lo) =================
// frag value = W[nt*16+(lane&15)][kk*32+(lane>>4)*8+i], flat [kk][nt][lane][i]
__global__ void prep_wmsg(const float* __restrict__ W, ushort_t* __restrict__ hi,
                          ushort_t* __restrict__ lo){
    int idx = blockIdx.x * blockDim.x + threadIdx.x;
    const int per = 4 * 8 * 512;
    if (idx >= 21 * per) return;
    int layer = idx / per, r = idx % per;
    int kk = r / 4096, nt = (r / 512) & 7, lane = (r / 8) & 63, i = r & 7;
    int c = nt * 16 + (lane & 15);
    int k = kk * 32 + (lane >> 4) * 8 + i;
    float w = W[(size_t)layer * 16384 + c * 128 + k];
    unsigned short h = f2h(w);
    hi[idx] = h; lo[idx] = f2h(w - h2f(h));
}

__global__ void prep_wupd(const float* __restrict__ W, ushort_t* __restrict__ hi,
                          ushort_t* __restrict__ lo){
    int idx = blockIdx.x * blockDim.x + threadIdx.x;
    const int per = 8 * 8 * 512;
    if (idx >= 21 * per) return;
    int layer = idx / per, r = idx % per;
    int kk = r / 4096, nt = (r / 512) & 7, lane = (r / 8) & 63, i = r & 7;
    int c = nt * 16 + (lane & 15);
    int k = kk * 32 + (lane >> 4) * 8 + i;
    float w = W[(size_t)layer * 32768 + c * 256 + k];
    unsigned short h = f2h(w);
    hi[idx] = h; lo[idx] = f2h(w - h2f(h));
}

__global__ void prep_mlp(const float* __restrict__ W1, const float* __restrict__ W2,
                         const float* __restrict__ W3,
                         ushort_t* w1h, ushort_t* w1l,
                         ushort_t* w2h, ushort_t* w2l,
                         ushort_t* w3h, ushort_t* w3l){
    int idx = blockIdx.x * blockDim.x + threadIdx.x;
    if (idx >= 73728) return;
    const float* W; ushort_t *ph, *pl; int NT, Kld, nc, local;
    if (idx < 32768)      { local = idx;         W = W1; ph = w1h; pl = w1l; NT = 16; Kld = 128; nc = 256; }
    else if (idx < 65536) { local = idx - 32768; W = W2; ph = w2h; pl = w2l; NT = 8;  Kld = 256; nc = 128; }
    else                  { local = idx - 65536; W = W3; ph = w3h; pl = w3l; NT = 4;  Kld = 128; nc = 63;  }
    int i = local & 7, lane = (local >> 3) & 63, nt = (local >> 9) % NT, kk = local / (512 * NT);
    int c = nt * 16 + (lane & 15);
    int k = kk * 32 + (lane >> 4) * 8 + i;
    float w = (c < nc) ? W[c * Kld + k] : 0.f;
    unsigned short h = f2h(w);
    ph[local] = h; pl[local] = f2h(w - h2f(h));
}

// ================= GEMM core: fp16 A single, fp16 B hi/lo (2 MFMAs) =================
template<int KK1, int KK2, int NT>
__device__ __forceinline__ void core_f16(
    const ushort_t* __restrict__ A1, const ushort_t* __restrict__ A2,
    const ushort_t* __restrict__ Bh, const ushort_t* __restrict__ Bl,
    int NTtot, int nt0, int waveRow0, int lane, f32x4 (&acc)[NT])
{
    const int lm = lane & 15;
    const int lk = (lane >> 4) * 8;
#pragma unroll
    for (int kk = 0; kk < KK1 + KK2; ++kk){
        const ushort_t* ap; int ld, kc;
        if (kk < KK1){ ap = A1; ld = KK1 * 32; kc = kk * 32 + lk; }
        else         { ap = A2; ld = KK2 * 32; kc = (kk - KK1) * 32 + lk; }
        f16x8 af = *reinterpret_cast<const f16x8*>(ap + (size_t)(waveRow0 + lm) * ld + kc); // unguarded; tail pad
        const ushort_t* bp = Bh + ((size_t)(kk * NTtot + nt0)) * 512 + lane * 8;
        const ushort_t* bq = Bl + ((size_t)(kk * NTtot + nt0)) * 512 + lane * 8;
#pragma unroll
        for (int nt = 0; nt < NT; ++nt){
            f16x8 bh = *reinterpret_cast<const f16x8*>(bp + nt * 512);
            f16x8 bl = *reinterpret_cast<const f16x8*>(bq + nt * 512);
            acc[nt] = __builtin_amdgcn_mfma_f32_16x16x32_f16(af, bh, acc[nt], 0, 0, 0);
            acc[nt] = __builtin_amdgcn_mfma_f32_16x16x32_f16(af, bl, acc[nt], 0, 0, 0);
        }
    }
}

// LDS tile: 64 rows x 136 ushorts (272-B stride, 16-B aligned, bank-spread)
#define LDS_STRIDE 136

// stage one wave's 16x(NT*16) fp16 tile into LDS. ACT: 0 none, 1 relu, 2 tanh
template<int NT, int ACT, bool HAS_BIAS>
__device__ __forceinline__ void epi_stage(
    f32x4 (&acc)[NT], const float* __restrict__ bias, int colOffE,
    ushort_t* lds, int w, int lane)
{
    const int lm = lane & 15;
    const int cr = (lane >> 4) * 4;
#pragma unroll
    for (int nt = 0; nt < NT; ++nt){
        float bv = HAS_BIAS ? bias[colOffE + nt * 16 + lm] : 0.f;
#pragma unroll
        for (int j = 0; j < 4; ++j){
            float v = acc[nt][j] + bv;
            if (ACT == 1) v = v > 0.f ? v : 0.f;
            else if (ACT == 2) v = tanhf(v);
            lds[(w * 16 + cr + j) * LDS_STRIDE + nt * 16 + lm] = f2h(v);
        }
    }
}

// flat coalesced flush of the block's 64x128 fp16 tile (call after __syncthreads)
__device__ __forceinline__ void flush_tile(
    const ushort_t* lds, ushort_t* __restrict__ out,
    int blockRow0, int ldcE, int colOffE, int tid)
{
#pragma unroll
    for (int it = 0; it < 4; ++it){
        int idx  = it * 256 + tid;        // 1024 chunks of 16 B
        int row  = idx >> 4;
        int colE = (idx & 15) * 8;
        int g = blockRow0 + row;
        if (g < NN)
            *reinterpret_cast<s16x8*>(out + (size_t)g * ldcE + colOffE + colE) =
                *reinterpret_cast<const s16x8*>(lds + row * LDS_STRIDE + colE);
    }
}

// OUTMODE: 0 = fp32 direct (Cf), 2 = fp16 LDS-staged (Cs)
template<int KK1, int NT, int ACT, bool HAS_BIAS, int OUTMODE>
__global__ __launch_bounds__(256) void gemm_f16(
    const ushort_t* __restrict__ A1,
    const ushort_t* __restrict__ Bh, const ushort_t* __restrict__ Bl, int NTtot,
    const float* __restrict__ bias,
    ushort_t* __restrict__ Cs, float* __restrict__ Cf, int ldcE, int ncols)
{
    __shared__ ushort_t lds[64 * LDS_STRIDE];
    const int lane = threadIdx.x & 63;
    const int w    = threadIdx.x >> 6;
    const int nt0  = blockIdx.y * NT;
    const int colOffE = blockIdx.y * (NT * 16);
    const int waveRow0 = blockIdx.x * 64 + w * 16;
    f32x4 acc[NT];
#pragma unroll
    for (int nt = 0; nt < NT; ++nt)
#pragma unroll
        for (int j = 0; j < 4; ++j) acc[nt][j] = 0.f;
    core_f16<KK1, 0, NT>(A1, nullptr, Bh, Bl, NTtot, nt0, waveRow0, lane, acc);

    if constexpr (OUTMODE == 2){
        epi_stage<NT, ACT, HAS_BIAS>(acc, bias, colOffE, lds, w, lane);
        __syncthreads();
        flush_tile(lds, Cs, blockIdx.x * 64, ldcE, colOffE, threadIdx.x);
    } else {
        const int lm = lane & 15;
        const int cr = (lane >> 4) * 4;
#pragma unroll
        for (int nt = 0; nt < NT; ++nt){
            int col = colOffE + nt * 16 + lm;
            if (col >= ncols) continue;
            float bv = HAS_BIAS ? bias[col] : 0.f;
#pragma unroll
            for (int j = 0; j < 4; ++j){
                int g = waveRow0 + cr + j;
                if (g < NN){
                    float v = acc[nt][j] + bv;
                    if (ACT == 1) v = v > 0.f ? v : 0.f;
                    else if (ACT == 2) v = tanhf(v);
                    Cf[(size_t)g * ldcE + col] = v;
                }
            }
        }
    }
}

// fused: h' = relu([aggr|h] Wu^T) -> h_out ; m' = tanh(h' Wm^T + bm) -> m_out
// phase-2 A comes straight from the LDS tile (never re-read from global)
template<bool WITH_MSG>
__global__ __launch_bounds__(256) void fused_update_msg(
    const ushort_t* __restrict__ ag, const ushort_t* __restrict__ h,
    const ushort_t* __restrict__ Wuh, const ushort_t* __restrict__ Wul,
    const ushort_t* __restrict__ Wmh, const ushort_t* __restrict__ Wml,
    const float* __restrict__ bm,
    ushort_t* __restrict__ h_out, ushort_t* __restrict__ m_out)
{
    __shared__ ushort_t lds[64 * LDS_STRIDE];
    const int lane = threadIdx.x & 63;
    const int w    = threadIdx.x >> 6;
    const int waveRow0 = blockIdx.x * 64 + w * 16;
    const int lm = lane & 15;
    const int lk = (lane >> 4) * 8;

    f32x4 acc[8];
#pragma unroll
    for (int nt = 0; nt < 8; ++nt)
#pragma unroll
        for (int j = 0; j < 4; ++j) acc[nt][j] = 0.f;
    core_f16<4, 4, 8>(ag, h, Wuh, Wul, 8, 0, waveRow0, lane, acc);
    epi_stage<8, 1, false>(acc, nullptr, 0, lds, w, lane);
    __syncthreads();
    flush_tile(lds, h_out, blockIdx.x * 64, 128, 0, threadIdx.x);

    if constexpr (WITH_MSG){
        __syncthreads();   // all flush reads done before any epi-2 LDS overwrite
        f32x4 acc2[8];
#pragma unroll
        for (int nt = 0; nt < 8; ++nt)
#pragma unroll
            for (int j = 0; j < 4; ++j) acc2[nt][j] = 0.f;
#pragma unroll
        for (int kk = 0; kk < 4; ++kk){
            f16x8 af = *reinterpret_cast<const f16x8*>(lds + (w * 16 + lm) * LDS_STRIDE + kk * 32 + lk);
            const ushort_t* bp = Wmh + (size_t)(kk * 8) * 512 + lane * 8;
            const ushort_t* bq = Wml + (size_t)(kk * 8) * 512 + lane * 8;
#pragma unroll
            for (int nt = 0; nt < 8; ++nt){
                f16x8 bh = *reinterpret_cast<const f16x8*>(bp + nt * 512);
                f16x8 bl = *reinterpret_cast<const f16x8*>(bq + nt * 512);
                acc2[nt] = __builtin_amdgcn_mfma_f32_16x16x32_f16(af, bh, acc2[nt], 0, 0, 0);
                acc2[nt] = __builtin_amdgcn_mfma_f32_16x16x32_f16(af, bl, acc2[nt], 0, 0, 0);
            }
        }
        epi_stage<8, 2, true>(acc2, bm, 0, lds, w, lane);   // own-region writes after own A-reads
        __syncthreads();
        flush_tile(lds, m_out, blockIdx.x * 64, 128, 0, threadIdx.x);
    }
}

// ================= aggregation: aggr[n] = m[n] + sum m[src]; fp16, unroll 4 =================
__global__ __launch_bounds__(256) void aggregate_kernel(
    const ushort_t* __restrict__ m,
    const int* __restrict__ row_start, const int* __restrict__ cols,
    ushort_t* __restrict__ ag)
{
    int wid  = (blockIdx.x * 256 + threadIdx.x) >> 6;
    int lane = threadIdx.x & 63;
    int s0 = row_start[wid], s1 = row_start[wid + 1];
    const uint_t* mp = (const uint_t*)m;           // row = 64 uints (2 fp16 each)
    size_t self = (size_t)wid * 64 + lane;
    uint_t v = mp[self];
    float a0 = h2f((unsigned short)v);
    float a1 = h2f((unsigned short)(v >> 16));
    int e = s0;
    for (; e + 3 < s1; e += 4){
        uint_t v0 = mp[(size_t)cols[e]     * 64 + lane];
        uint_t v1 = mp[(size_t)cols[e + 1] * 64 + lane];
        uint_t v2 = mp[(size_t)cols[e + 2] * 64 + lane];
        uint_t v3 = mp[(size_t)cols[e + 3] * 64 + lane];
        a0 += h2f((unsigned short)v0) + h2f((unsigned short)v1)
            + h2f((unsigned short)v2) + h2f((unsigned short)v3);
        a1 += h2f((unsigned short)(v0 >> 16)) + h2f((unsigned short)(v1 >> 16))
            + h2f((unsigned short)(v2 >> 16)) + h2f((unsigned short)(v3 >> 16));
    }
    for (; e < s1; ++e){
        uint_t v0 = mp[(size_t)cols[e] * 64 + lane];
        a0 += h2f((unsigned short)v0);
        a1 += h2f((unsigned short)(v0 >> 16));
    }
    ((uint_t*)ag)[self] = (uint_t)f2h(a0) | ((uint_t)f2h(a1) << 16);
}

// ================= host =================
extern "C" void kernel_launch(void* const* d_in, const int* in_sizes, int n_in,
                              void* d_out, int out_size, void* d_ws, size_t ws_size,
                              hipStream_t stream)
{
    const float* x     = (const float*)d_in[0];
    const int*   ei    = (const int*)d_in[1];
    const float* W_msg = (const float*)d_in[3];
    const float* b_msg = (const float*)d_in[4];
    const float* W_upd = (const float*)d_in[5];
    const float* W1    = (const float*)d_in[6];
    const float* b1    = (const float*)d_in[7];
    const float* W2    = (const float*)d_in[8];
    const float* b2    = (const float*)d_in[9];
    const float* W3    = (const float*)d_in[10];
    const float* b3    = (const float*)d_in[11];
    const int* srcp = ei;
    const int* dstp = ei + NE;

    char* ws = (char*)d_ws;
    size_t off = 0;
    auto carve = [&](size_t bytes) -> void* {
        void* p = ws + off;
        off += (bytes + 255) & ~(size_t)255;
        return p;
    };
    const size_t FBUF = (size_t)NN * 128 * 2;   // 12.8 MB fp16 node buffer
    // carve order matters: (m, ag) adjacent -> h1 (N x 256 fp16) overlay
    ushort_t* xf = (ushort_t*)carve(FBUF);      // x fp16; later h ping / h2
    ushort_t* hA = (ushort_t*)carve(FBUF);      // h ping
    ushort_t* m  = (ushort_t*)carve(FBUF);      // messages; later h1 lo half
    ushort_t* ag = (ushort_t*)carve(FBUF);      // aggr;     later h1 hi half

    int* counts    = (int*)carve((size_t)NN * 4);
    int* cursor    = (int*)carve((size_t)NN * 4);
    int* row_start = (int*)carve(((size_t)NN + 1) * 4);
    int* bsum      = (int*)carve(256 * 4);
    int* boff      = (int*)carve(256 * 4);
    int* colv      = (int*)carve((size_t)NE * 4);

    ushort_t* wmsg_hi = (ushort_t*)carve((size_t)21 * 16384 * 2);
    ushort_t* wmsg_lo = (ushort_t*)carve((size_t)21 * 16384 * 2);
    ushort_t* wupd_hi = (ushort_t*)carve((size_t)21 * 32768 * 2);
    ushort_t* wupd_lo = (ushort_t*)carve((size_t)21 * 32768 * 2);
    ushort_t* w1_hi   = (ushort_t*)carve(32768 * 2);
    ushort_t* w1_lo   = (ushort_t*)carve(32768 * 2);
    ushort_t* w2_hi   = (ushort_t*)carve(32768 * 2);
    ushort_t* w2_lo   = (ushort_t*)carve(32768 * 2);
    ushort_t* w3_hi   = (ushort_t*)carve(8192 * 2);
    ushort_t* w3_lo   = (ushort_t*)carve(8192 * 2);
    (void)carve(65536);   // tail pad: unguarded A-loads overrun < 13 KB

    const int NB = (NN + 255) / 256;   // 196
    const int GB = (NN + 63) / 64;     // 782 (one 64-row tile per block)

    // CSR
    hipMemsetAsync(counts, 0, (size_t)NN * 4, stream);
    hist_kernel<<<(NE + 255) / 256, 256, 0, stream>>>(dstp, counts);
    blocksum_kernel<<<NB, 256, 0, stream>>>(counts, bsum);
    scanb_kernel<<<1, 256, 0, stream>>>(bsum, boff, row_start, NB);
    localscan_kernel<<<NB, 256, 0, stream>>>(counts, boff, row_start, cursor);
    scatter_kernel<<<(NE + 255) / 256, 256, 0, stream>>>(srcp, dstp, cursor, colv);

    // prep
    convert_x_kernel<<<(NN * 32 + 255) / 256, 256, 0, stream>>>(x, xf);
    prep_wmsg<<<(21 * 16384 + 255) / 256, 256, 0, stream>>>(W_msg, wmsg_hi, wmsg_lo);
    prep_wupd<<<(21 * 32768 + 255) / 256, 256, 0, stream>>>(W_upd, wupd_hi, wupd_lo);
    prep_mlp<<<288, 256, 0, stream>>>(W1, W2, W3, w1_hi, w1_lo, w2_hi, w2_lo, w3_hi, w3_lo);

    // m_0 = tanh(x Wm_0^T + bm_0)
    gemm_f16<4, 8, 2, true, 2><<<GB, 256, 0, stream>>>(
        xf, wmsg_hi, wmsg_lo, 8, b_msg, m, nullptr, 128, 128);

    // 21 layers; h ping-pongs xf <-> hA
    const ushort_t* cur = xf;
    ushort_t* nxt = hA;
    for (int l = 0; l < 21; ++l){
        aggregate_kernel<<<NN / 4, 256, 0, stream>>>(m, row_start, colv, ag);
        if (l < 20){
            fused_update_msg<true><<<GB, 256, 0, stream>>>(
                ag, cur,
                wupd_hi + (size_t)l * 32768, wupd_lo + (size_t)l * 32768,
                wmsg_hi + (size_t)(l + 1) * 16384, wmsg_lo + (size_t)(l + 1) * 16384,
                b_msg + (size_t)(l + 1) * 128,
                nxt, m);
        } else {
            fused_update_msg<false><<<GB, 256, 0, stream>>>(
                ag, cur,
                wupd_hi + (size_t)l * 32768, wupd_lo + (size_t)l * 32768,
                nullptr, nullptr, nullptr,
                nxt, nullptr);
        }
        const ushort_t* t = cur; cur = nxt; nxt = (ushort_t*)t;
    }
    // after 21 layers (l=20 wrote hA): cur == hA; xf, m, ag free

    // MLP head: h1 (N x 256 fp16) overlays m..ag span; h2 = xf
    ushort_t* h1 = m;
    gemm_f16<4, 8, 1, true, 2><<<dim3(GB, 2), 256, 0, stream>>>(
        cur, w1_hi, w1_lo, 16, b1, h1, nullptr, 256, 256);
    gemm_f16<8, 8, 1, true, 2><<<GB, 256, 0, stream>>>(
        h1, w2_hi, w2_lo, 8, b2, xf, nullptr, 128, 128);
    gemm_f16<4, 4, 0, true, 0><<<GB, 256, 0, stream>>>(
        xf, w3_hi, w3_lo, 4, b3, nullptr, (float*)d_out, 63, 63);
}